// Round 5
// baseline (97.579 us; speedup 1.0000x reference)
//
#include <hip/hip_runtime.h>
#include <math.h>

#define M_ROWS 8192   // B*S
#define KDIM   8192   // V
#define NDIM   512    // D
#define CH     512    // elements scanned per wave-iteration
#define NIT    (KDIM / CH)   // 16

typedef float    f32x4  __attribute__((ext_vector_type(4)));
typedef unsigned u32x4  __attribute__((ext_vector_type(4)));
typedef __bf16   bf16x8 __attribute__((ext_vector_type(8)));

// ---------------------------------------------------------------------------
// Kernel 1: W [512, 8192] f32 -> WT [8192, 512] bf16 (d_ws, 8 MB).
// 64x64 LDS tile; pad 65 (65*8 % 32 = 8 -> 2-way max, free).
__global__ __launch_bounds__(256)
void transpose_w(const float* __restrict__ W, __bf16* __restrict__ WT) {
  __shared__ float tile[64][65];
  const int t  = threadIdx.x;
  const int v0 = (blockIdx.x & 127) << 6;
  const int d0 = (blockIdx.x >> 7) << 6;
  #pragma unroll
  for (int i = 0; i < 4; ++i) {
    int idx = i * 256 + t;
    int r = idx >> 4;                 // d-row 0..63
    int c = (idx & 15) << 2;          // v-col
    f32x4 val = __builtin_nontemporal_load(
        (const f32x4*)(W + (size_t)(d0 + r) * KDIM + v0 + c));
    tile[r][c + 0] = val.x; tile[r][c + 1] = val.y;
    tile[r][c + 2] = val.z; tile[r][c + 3] = val.w;
  }
  __syncthreads();
  #pragma unroll
  for (int i = 0; i < 2; ++i) {
    int idx = i * 256 + t;
    int vr = idx >> 3;                // v-row 0..63
    int d8 = (idx & 7) << 3;          // d-col
    bf16x8 u;
    #pragma unroll
    for (int j = 0; j < 8; ++j) u[j] = (__bf16)tile[d8 + j][vr];
    *(bf16x8*)(WT + (size_t)(v0 + vr) * NDIM + d0 + d8) = u;
  }
}

// ---------------------------------------------------------------------------
// Kernel 2: sparse SpMM + tanh. One wave per output row m (exact for any
// density). A-scan: nontemporal f32x4 streams (no L2 pollution -> WT stays
// L2-resident). Nonzeros enumerated via ballot; gathers pair-batched so two
// 16B loads are in flight per exposed latency. Lane l owns C cols l*8..l*8+7.
__global__ __launch_bounds__(256, 4)
void spmm_tanh(const float* __restrict__ A, const __bf16* __restrict__ WT,
               float* __restrict__ C) {
  const int lane = threadIdx.x & 63;
  const int m    = blockIdx.x * 4 + (threadIdx.x >> 6);
  const float* arow = A + (size_t)m * KDIM;
  const char*  wtb  = (const char*)WT;

  float a0 = 0.f, a1 = 0.f, a2 = 0.f, a3 = 0.f,
        a4 = 0.f, a5 = 0.f, a6 = 0.f, a7 = 0.f;

#define FMA8(f, q)                                                          \
  {                                                                         \
    a0 = fmaf(f, __uint_as_float((q).x << 16), a0);                         \
    a1 = fmaf(f, __uint_as_float((q).x & 0xffff0000u), a1);                 \
    a2 = fmaf(f, __uint_as_float((q).y << 16), a2);                         \
    a3 = fmaf(f, __uint_as_float((q).y & 0xffff0000u), a3);                 \
    a4 = fmaf(f, __uint_as_float((q).z << 16), a4);                         \
    a5 = fmaf(f, __uint_as_float((q).z & 0xffff0000u), a5);                 \
    a6 = fmaf(f, __uint_as_float((q).w << 16), a6);                         \
    a7 = fmaf(f, __uint_as_float((q).w & 0xffff0000u), a7);                 \
  }

#define PROC(av, basev)                                                     \
  {                                                                         \
    _Pragma("unroll")                                                       \
    for (int j = 0; j < 4; ++j) {                                           \
      unsigned long long mask = __ballot((av)[j] != 0.0f);                  \
      while (mask) {  /* wave-uniform */                                    \
        int s0 = __builtin_ctzll(mask); mask &= mask - 1;                   \
        bool two = (mask != 0);                                             \
        int s1 = two ? __builtin_ctzll(mask) : s0;                          \
        if (two) mask &= mask - 1;                                          \
        float f0 = __shfl((av)[j], s0, 64);                                 \
        float f1 = __shfl((av)[j], s1, 64);                                 \
        if (!two) f1 = 0.0f;                                                \
        int v0i = (basev) + s0 * 4 + j;                                     \
        int v1i = (basev) + s1 * 4 + j;                                     \
        u32x4 q0 = *(const u32x4*)(wtb + (size_t)v0i * (NDIM * 2) + lane * 16); \
        u32x4 q1 = *(const u32x4*)(wtb + (size_t)v1i * (NDIM * 2) + lane * 16); \
        FMA8(f0, q0);                                                       \
        FMA8(f1, q1);                                                       \
      }                                                                     \
    }                                                                       \
  }

  // prologue: chunk 0 in regs
  f32x4 c0 = __builtin_nontemporal_load((const f32x4*)(arow + lane * 4));
  f32x4 c1 = __builtin_nontemporal_load((const f32x4*)(arow + 256 + lane * 4));

  for (int it = 0; it < NIT; ++it) {
    f32x4 n0, n1;
    if (it + 1 < NIT) {
      const float* nx = arow + (size_t)(it + 1) * CH;
      n0 = __builtin_nontemporal_load((const f32x4*)(nx + lane * 4));
      n1 = __builtin_nontemporal_load((const f32x4*)(nx + 256 + lane * 4));
    }
    PROC(c0, it * CH);
    PROC(c1, it * CH + 256);
    if (it + 1 < NIT) { c0 = n0; c1 = n1; }
  }

  float* crow = C + (size_t)m * NDIM + lane * 8;
  f32x4 o0 = {tanhf(a0), tanhf(a1), tanhf(a2), tanhf(a3)};
  f32x4 o1 = {tanhf(a4), tanhf(a5), tanhf(a6), tanhf(a7)};
  __builtin_nontemporal_store(o0, (f32x4*)(crow + 0));
  __builtin_nontemporal_store(o1, (f32x4*)(crow + 4));
#undef PROC
#undef FMA8
}

// ---------------------------------------------------------------------------
extern "C" void kernel_launch(void* const* d_in, const int* in_sizes, int n_in,
                              void* d_out, int out_size, void* d_ws, size_t ws_size,
                              hipStream_t stream) {
  const float* x = (const float*)d_in[0];  // [8192, 8192] f32
  const float* W = (const float*)d_in[1];  // [512, 8192]  f32
  float* out = (float*)d_out;              // [8192, 512]  f32
  __bf16* WT = (__bf16*)d_ws;              // [8192, 512]  bf16

  transpose_w<<<dim3(1024), dim3(256), 0, stream>>>(W, WT);
  spmm_tanh  <<<dim3(M_ROWS / 4), dim3(256), 0, stream>>>(x, WT, out);
}

// Round 6
// 96.541 us; speedup vs baseline: 1.0107x; 1.0107x over previous
//
#include <hip/hip_runtime.h>
#include <math.h>

#define M_ROWS 8192   // B*S
#define KDIM   8192   // V
#define NDIM   512    // D
#define CAP    512    // LDS pair slots per wave (mean nnz/row ~82, 47-sigma margin)

typedef float    f32x4  __attribute__((ext_vector_type(4)));
typedef unsigned u32x4  __attribute__((ext_vector_type(4)));
typedef __bf16   bf16x8 __attribute__((ext_vector_type(8)));

// ---------------------------------------------------------------------------
// Kernel 1: W [512, 8192] f32 -> WT [8192, 512] bf16 (d_ws, 8 MB).
__global__ __launch_bounds__(256)
void transpose_w(const float* __restrict__ W, __bf16* __restrict__ WT) {
  __shared__ float tile[64][65];
  const int t  = threadIdx.x;
  const int v0 = (blockIdx.x & 127) << 6;
  const int d0 = (blockIdx.x >> 7) << 6;
  #pragma unroll
  for (int i = 0; i < 4; ++i) {
    int idx = i * 256 + t;
    int r = idx >> 4;
    int c = (idx & 15) << 2;
    f32x4 val = __builtin_nontemporal_load(
        (const f32x4*)(W + (size_t)(d0 + r) * KDIM + v0 + c));
    tile[r][c + 0] = val.x; tile[r][c + 1] = val.y;
    tile[r][c + 2] = val.z; tile[r][c + 3] = val.w;
  }
  __syncthreads();
  #pragma unroll
  for (int i = 0; i < 2; ++i) {
    int idx = i * 256 + t;
    int vr = idx >> 3;
    int d8 = (idx & 7) << 3;
    bf16x8 u;
    #pragma unroll
    for (int j = 0; j < 8; ++j) u[j] = (__bf16)tile[d8 + j][vr];
    *(bf16x8*)(WT + (size_t)(v0 + vr) * NDIM + d0 + d8) = u;
  }
}

// ---------------------------------------------------------------------------
// Kernel 2: two-phase per wave.
//  Phase 1: stream row, ballot-compact nonzeros (fbits, v) into wave-private
//           LDS list — NO gathers interleaved, so scan loads pipeline freely.
//  Phase 2: drain list with 4-deep gather pipeline; pair reads are LDS
//           (lgkmcnt), so vmcnt waits count ONLY gathers -> counted vmcnt(3..0).
// Exact for any density: ballot enumerates actual nonzeros; LDS overflow
// (cur+cnt > CAP, never at ~1%) falls back to exact inline gather+FMA.
__global__ __launch_bounds__(256)
void spmm_tanh(const float* __restrict__ A, const __bf16* __restrict__ WT,
               float* __restrict__ C) {
  __shared__ uint2 plist[4][CAP];   // 16 KB/block, wave-private slices
  const int lane = threadIdx.x & 63;
  const int w    = threadIdx.x >> 6;
  const int m    = blockIdx.x * 4 + w;
  const float* arow = A + (size_t)m * KDIM;
  const char*  wtb  = (const char*)WT;

  float a0 = 0.f, a1 = 0.f, a2 = 0.f, a3 = 0.f,
        a4 = 0.f, a5 = 0.f, a6 = 0.f, a7 = 0.f;

#define FMA8(f, q)                                                          \
  {                                                                         \
    a0 = fmaf(f, __uint_as_float((q).x << 16), a0);                         \
    a1 = fmaf(f, __uint_as_float((q).x & 0xffff0000u), a1);                 \
    a2 = fmaf(f, __uint_as_float((q).y << 16), a2);                         \
    a3 = fmaf(f, __uint_as_float((q).y & 0xffff0000u), a3);                 \
    a4 = fmaf(f, __uint_as_float((q).z << 16), a4);                         \
    a5 = fmaf(f, __uint_as_float((q).z & 0xffff0000u), a5);                 \
    a6 = fmaf(f, __uint_as_float((q).w << 16), a6);                         \
    a7 = fmaf(f, __uint_as_float((q).w & 0xffff0000u), a7);                 \
  }

  // ---- Phase 1: stream + compact
  int cur = 0;
  const unsigned long long ltmask = (lane == 63) ? ~0ull >> 1 : (1ull << lane) - 1;
  #pragma unroll 4
  for (int it = 0; it < KDIM / 256; ++it) {      // 32 iters x 1 KB/wave
    f32x4 av = __builtin_nontemporal_load((const f32x4*)(arow + it * 256 + lane * 4));
    #pragma unroll
    for (int j = 0; j < 4; ++j) {
      unsigned long long msk = __ballot(av[j] != 0.0f);
      if (msk == 0) continue;                     // ~53% of groups
      int cnt = __popcll(msk);
      if (cur + cnt <= CAP) {
        if (av[j] != 0.0f) {
          int pre = __popcll(msk & ltmask);
          plist[w][cur + pre] =
              make_uint2(__float_as_uint(av[j]),
                         (unsigned)(it * 256 + lane * 4 + j));
        }
        cur += cnt;
      } else {
        // exact overflow path (statistically never taken at ~1% density)
        while (msk) {
          int s = __builtin_ctzll(msk); msk &= msk - 1;
          float f = __shfl(av[j], s, 64);
          int v = it * 256 + s * 4 + j;
          u32x4 q = *(const u32x4*)(wtb + (size_t)v * (NDIM * 2) + lane * 16);
          FMA8(f, q);
        }
      }
    }
  }

  // ---- Phase 2: 4-deep static gather pipeline from the LDS list
  const int n = cur;
  if (n > 0) {
    const int ng = (n + 3) >> 2;
    // pair reader with branchless zero-padding past n
    auto rdp = [&](int i) -> uint2 {
      uint2 p = plist[w][i < CAP ? (i < n ? i : n - 1) : CAP - 1];
      if (i >= n) { p.x = 0u; p.y = 0u; }         // f=0 -> row-0 gather, adds 0
      return p;
    };
    uint2 p0 = rdp(0), p1 = rdp(1), p2 = rdp(2), p3 = rdp(3);
    for (int t = 0; t < ng; ++t) {
      const float    f0 = __uint_as_float(p0.x), f1 = __uint_as_float(p1.x);
      const float    f2 = __uint_as_float(p2.x), f3 = __uint_as_float(p3.x);
      const unsigned v0 = p0.y, v1 = p1.y, v2 = p2.y, v3 = p3.y;
      // 4 independent gathers in flight (vmcnt counts only these)
      u32x4 q0 = *(const u32x4*)(wtb + (size_t)v0 * (NDIM * 2) + lane * 16);
      u32x4 q1 = *(const u32x4*)(wtb + (size_t)v1 * (NDIM * 2) + lane * 16);
      u32x4 q2 = *(const u32x4*)(wtb + (size_t)v2 * (NDIM * 2) + lane * 16);
      u32x4 q3 = *(const u32x4*)(wtb + (size_t)v3 * (NDIM * 2) + lane * 16);
      // prefetch next pair group from LDS (lgkmcnt — doesn't drain gathers)
      if (t + 1 < ng) {
        int b = (t + 1) * 4;
        p0 = rdp(b); p1 = rdp(b + 1); p2 = rdp(b + 2); p3 = rdp(b + 3);
      }
      FMA8(f0, q0);
      FMA8(f1, q1);
      FMA8(f2, q2);
      FMA8(f3, q3);
    }
  }

  float* crow = C + (size_t)m * NDIM + lane * 8;
  f32x4 o0 = {tanhf(a0), tanhf(a1), tanhf(a2), tanhf(a3)};
  f32x4 o1 = {tanhf(a4), tanhf(a5), tanhf(a6), tanhf(a7)};
  __builtin_nontemporal_store(o0, (f32x4*)(crow + 0));
  __builtin_nontemporal_store(o1, (f32x4*)(crow + 4));
#undef FMA8
}

// ---------------------------------------------------------------------------
extern "C" void kernel_launch(void* const* d_in, const int* in_sizes, int n_in,
                              void* d_out, int out_size, void* d_ws, size_t ws_size,
                              hipStream_t stream) {
  const float* x = (const float*)d_in[0];  // [8192, 8192] f32
  const float* W = (const float*)d_in[1];  // [512, 8192]  f32
  float* out = (float*)d_out;              // [8192, 512]  f32
  __bf16* WT = (__bf16*)d_ws;              // [8192, 512]  bf16

  transpose_w<<<dim3(1024), dim3(256), 0, stream>>>(W, WT);
  spmm_tanh  <<<dim3(M_ROWS / 4), dim3(256), 0, stream>>>(x, WT, out);
}